// Round 7
// baseline (239493.042 us; speedup 1.0000x reference)
//
#include <hip/hip_runtime.h>

// Problem constants
#define T_SEQ   8192
#define N_RES   2048
#define K_IN    512

// Geometry: 64 blocks x 512 threads (8 waves); 32 rows/block, 4 rows/wave.
#define G_BLOCKS 64
#define B_THREADS 512
#define ROWS_PER_WAVE 4
#define ROWS_PER_BLOCK 32
static_assert(G_BLOCKS * ROWS_PER_BLOCK == N_RES, "row partition mismatch");

#define INV_SQRT_N 0.022097086912079612f

// Phase encoding: packet float e = phi*(v + ENC_OFF), phi alternates per ring
// generation (phi(g) = ((g>>1)&1) ? -1 : +1, slot = g&1). |v| <= 0.0222 so
// |e| in [0.078, 0.122]. Ready iff phi_expected*e > ENC_THR; stale (gen-2)
// packet has opposite phi -> not-ready; zero-init -> not-ready.
#define ENC_OFF 0.1f
#define ENC_THR 0.05f

typedef unsigned long long u64;
typedef unsigned int u32;

__device__ __forceinline__ float fast_tanh(float v) {
    float e = __expf(2.0f * v);
    return 1.0f - 2.0f / (e + 1.0f);
}

// AGPR pin: "+a" forces the value into an accumulation register. An asm
// output cannot be rematerialized from the original global-memory load, so
// the weight can never legally be re-fetched; a use costs one v_accvgpr_read.
#define PIN_A4(v) asm("" : "+a"((v).x), "+a"((v).y), "+a"((v).z), "+a"((v).w))

// d_ws layout: ring [2][1024] u64 (16 KB)
__global__ __launch_bounds__(B_THREADS, 2)
void reservoir_v7(const float* __restrict__ input,   // [T_SEQ][K_IN]
                  const float* __restrict__ state0,  // [N_RES]
                  const float* __restrict__ W_in,    // [N_RES][K_IN]
                  const float* __restrict__ W_res,   // [N_RES][N_RES]
                  float* __restrict__ out,           // [T_SEQ+1][N_RES]
                  u64* __restrict__ ring)
{
    const int tid  = threadIdx.x;
    const int lane = tid & 63;
    const int wave = tid >> 6;
    const int blk  = blockIdx.x;
    const int r0   = blk * ROWS_PER_BLOCK + wave * ROWS_PER_WAVE;

    __shared__ float s_lds[2][N_RES];   // double-buffered state (16 KB)

    // ---- persistent weights: lane l owns cols {4l+256i} ----
    float4 wr[ROWS_PER_WAVE][8];
    float4 wi[ROWS_PER_WAVE][2];
    #pragma unroll
    for (int k = 0; k < ROWS_PER_WAVE; ++k) {
        const float* rrow = W_res + (size_t)(r0 + k) * N_RES;
        #pragma unroll
        for (int i = 0; i < 8; ++i)
            wr[k][i] = *reinterpret_cast<const float4*>(rrow + 4 * lane + 256 * i);
        const float* irow = W_in + (size_t)(r0 + k) * K_IN;
        #pragma unroll
        for (int i = 0; i < 2; ++i)
            wi[k][i] = *reinterpret_cast<const float4*>(irow + 4 * lane + 256 * i);
    }
    // Force all 160 weight floats into AGPRs before the loop.
    #pragma unroll
    for (int k = 0; k < ROWS_PER_WAVE; ++k) {
        #pragma unroll
        for (int i = 0; i < 8; ++i) PIN_A4(wr[k][i]);
        PIN_A4(wi[k][0]); PIN_A4(wi[k][1]);
    }

    // out row 0 = initial state
    if (blk == 0)
        for (int j = tid; j < N_RES; j += B_THREADS) out[j] = state0[j];

    // s_0 -> LDS buffer 0 (covered by the in-loop __syncthreads at t=0)
    #pragma unroll
    for (int i = 0; i < 4; ++i)
        s_lds[0][i * 512 + tid] = state0[i * 512 + tid];

    // x row 0 (layout matches wi columns {4l+256i})
    float4 xa = *reinterpret_cast<const float4*>(input + 4 * lane);
    float4 xb = *reinterpret_cast<const float4*>(input + 4 * lane + 256);

    for (int t = 0; t < T_SEQ; ++t) {
        const int buf = t & 1;

        // issue x_{t+1} prefetch before the spin so HBM latency hides under it
        float4 xna = xa, xnb = xb;
        if (t + 1 < T_SEQ) {
            const float* xr = input + (size_t)(t + 1) * K_IN;
            xna = *reinterpret_cast<const float4*>(xr + 4 * lane);
            xnb = *reinterpret_cast<const float4*>(xr + 4 * lane + 256);
        }

        if (t > 0) {
            // ---- paced coalesced poll: 2 u64/thread covers the 1024-entry slot ----
            const u64* rp = ring + (buf << 10);
            const float phi = ((t >> 1) & 1) ? -1.0f : 1.0f;
            float2 sv2[2];
            u32 pend = 0x3u;
            while (pend) {
                #pragma unroll
                for (int i = 0; i < 2; ++i) {
                    if (pend & (1u << i)) {
                        u64 e = __hip_atomic_load(rp + i * 512 + tid,
                                                  __ATOMIC_RELAXED, __HIP_MEMORY_SCOPE_AGENT);
                        float lo = __uint_as_float((u32)e);
                        float hi = __uint_as_float((u32)(e >> 32));
                        if (phi * lo > ENC_THR && phi * hi > ENC_THR) {
                            sv2[i] = make_float2(fmaf(phi, lo, -ENC_OFF),
                                                 fmaf(phi, hi, -ENC_OFF));
                            pend &= ~(1u << i);
                        }
                    }
                }
                if (pend) __builtin_amdgcn_s_sleep(1);   // ~64cy backoff
            }
            #pragma unroll
            for (int i = 0; i < 2; ++i)
                *reinterpret_cast<float2*>(&s_lds[buf][2 * (i * 512 + tid)]) = sv2[i];
        }
        __syncthreads();

        // ---- input contribution ----
        float acc[ROWS_PER_WAVE];
        #pragma unroll
        for (int k = 0; k < ROWS_PER_WAVE; ++k) {
            float a = 0.0f;
            a = fmaf(wi[k][0].x, xa.x, a); a = fmaf(wi[k][0].y, xa.y, a);
            a = fmaf(wi[k][0].z, xa.z, a); a = fmaf(wi[k][0].w, xa.w, a);
            a = fmaf(wi[k][1].x, xb.x, a); a = fmaf(wi[k][1].y, xb.y, a);
            a = fmaf(wi[k][1].z, xb.z, a); a = fmaf(wi[k][1].w, xb.w, a);
            acc[k] = a;
        }

        // ---- state contribution from LDS (layout proven conflict-free) ----
        float4 sv[8];
        #pragma unroll
        for (int i = 0; i < 8; ++i)
            sv[i] = *reinterpret_cast<const float4*>(&s_lds[buf][4 * lane + 256 * i]);
        #pragma unroll
        for (int k = 0; k < ROWS_PER_WAVE; ++k) {
            float a = acc[k];
            #pragma unroll
            for (int i = 0; i < 8; ++i) {
                a = fmaf(wr[k][i].x, sv[i].x, a);
                a = fmaf(wr[k][i].y, sv[i].y, a);
                a = fmaf(wr[k][i].z, sv[i].z, a);
                a = fmaf(wr[k][i].w, sv[i].w, a);
            }
            acc[k] = a;
        }

        // ---- full-wave butterfly reduce (4 rows in flight) ----
        #pragma unroll
        for (int off = 32; off > 0; off >>= 1) {
            #pragma unroll
            for (int k = 0; k < ROWS_PER_WAVE; ++k)
                acc[k] += __shfl_xor(acc[k], off, 64);
        }

        // ---- finalize: publish first (critical path), out store off-path ----
        const float v0 = fast_tanh(acc[0]) * INV_SQRT_N;
        const float v1 = fast_tanh(acc[1]) * INV_SQRT_N;
        const float v2 = fast_tanh(acc[2]) * INV_SQRT_N;
        const float v3 = fast_tanh(acc[3]) * INV_SQRT_N;
        const int   slotn = (t + 1) & 1;
        const float phin  = (((t + 1) >> 1) & 1) ? -1.0f : 1.0f;
        if (lane == 0) {
            u64 pk = (u64)__float_as_uint(phin * (v0 + ENC_OFF)) |
                     ((u64)__float_as_uint(phin * (v1 + ENC_OFF)) << 32);
            __hip_atomic_store(ring + (slotn << 10) + (r0 >> 1), pk,
                               __ATOMIC_RELAXED, __HIP_MEMORY_SCOPE_AGENT);
        } else if (lane == 1) {
            u64 pk = (u64)__float_as_uint(phin * (v2 + ENC_OFF)) |
                     ((u64)__float_as_uint(phin * (v3 + ENC_OFF)) << 32);
            __hip_atomic_store(ring + (slotn << 10) + (r0 >> 1) + 1, pk,
                               __ATOMIC_RELAXED, __HIP_MEMORY_SCOPE_AGENT);
        } else if (lane == 2) {
            // per-wave out store (rows r0..r0+3) — lane-scoped, not tid-scoped
            *reinterpret_cast<float4*>(out + (size_t)(t + 1) * N_RES + r0) =
                make_float4(v0, v1, v2, v3);
        }

        // ---- re-pin at the back edge: no VGPR shadow copies may persist ----
        #pragma unroll
        for (int k = 0; k < ROWS_PER_WAVE; ++k) {
            #pragma unroll
            for (int i = 0; i < 8; ++i) PIN_A4(wr[k][i]);
            PIN_A4(wi[k][0]); PIN_A4(wi[k][1]);
        }

        xa = xna; xb = xnb;
    }
}

extern "C" void kernel_launch(void* const* d_in, const int* in_sizes, int n_in,
                              void* d_out, int out_size, void* d_ws, size_t ws_size,
                              hipStream_t stream) {
    const float* input  = (const float*)d_in[0];
    const float* state0 = (const float*)d_in[1];
    const float* W_in   = (const float*)d_in[2];
    const float* W_res  = (const float*)d_in[3];
    float* out = (float*)d_out;
    u64* ring  = (u64*)d_ws;

    // zero = "not ready" for both phases; re-cleared on every call/replay
    hipMemsetAsync(d_ws, 0, 2 * (N_RES / 2) * sizeof(u64), stream);

    void* args[] = { (void*)&input, (void*)&state0, (void*)&W_in, (void*)&W_res,
                     (void*)&out, (void*)&ring };
    hipLaunchCooperativeKernel((const void*)reservoir_v7,
                               dim3(G_BLOCKS), dim3(B_THREADS),
                               args, 0, stream);
}

// Round 8
// 29945.401 us; speedup vs baseline: 7.9977x; 7.9977x over previous
//
#include <hip/hip_runtime.h>

// Problem constants
#define T_SEQ   8192
#define N_RES   2048
#define K_IN    512

// Geometry: 64 blocks x 1024 threads (16 waves); 2 rows/wave via 32-lane groups.
#define G_BLOCKS 64
#define B_THREADS 1024
#define WAVES 16
static_assert(G_BLOCKS * WAVES * 2 == N_RES, "row partition mismatch");

#define INV_SQRT_N 0.022097086912079612f

// Phase encoding: packet float e = phi*(v + ENC_OFF), phi alternates per ring
// generation (phi(g) = ((g>>1)&1) ? -1 : +1, slot = g&1). |v| <= 0.0222 so
// |e| in [0.078, 0.122]. Ready iff phi_expected*e > ENC_THR; stale (gen-2)
// packet has opposite phi -> not-ready; zero-init -> not-ready.
#define ENC_OFF 0.1f
#define ENC_THR 0.05f

typedef unsigned long long u64;
typedef unsigned int u32;
typedef unsigned short u16;

__device__ __forceinline__ float fast_tanh(float v) {
    float e = __expf(2.0f * v);
    return 1.0f - 2.0f / (e + 1.0f);
}
// unpack 2 bf16 (packed little-endian in one u32) to 2 f32
__device__ __forceinline__ float2 bf2(u32 u) {
    return make_float2(__uint_as_float(u << 16),
                       __uint_as_float(u & 0xFFFF0000u));
}

// f32 -> bf16 round-to-nearest-even repack (runs every call; ~20 us)
__global__ void repack_bf16(const float* __restrict__ src, u16* __restrict__ dst,
                            int n) {
    int i = blockIdx.x * blockDim.x + threadIdx.x;
    if (i < n) {
        u32 u = __float_as_uint(src[i]);
        dst[i] = (u16)((u + 0x7FFFu + ((u >> 16) & 1u)) >> 16);
    }
}

// d_ws layout: ring [2][1024] u64 (16 KB) | @64KB: W_res bf16 (8 MB) | W_in bf16 (2 MB)
template<bool BF16W>
__global__ __launch_bounds__(B_THREADS, 4)
void reservoir_v8(const float* __restrict__ input,   // [T_SEQ][K_IN]
                  const float* __restrict__ state0,  // [N_RES]
                  const float* __restrict__ W_in,    // [N_RES][K_IN]
                  const float* __restrict__ W_res,   // [N_RES][N_RES]
                  const u16* __restrict__ Wres_bf,
                  const u16* __restrict__ Win_bf,
                  float* __restrict__ out,           // [T_SEQ+1][N_RES]
                  u64* __restrict__ ring)
{
    const int tid   = threadIdx.x;
    const int lane  = tid & 63;
    const int wave  = tid >> 6;
    const int blk   = blockIdx.x;
    const int c32   = lane & 31;              // column-slice within 32-lane row group
    const int row   = blk * 32 + wave * 2 + (lane >> 5);
    const int entry = blk * 16 + wave;        // this wave's packet: rows 2e, 2e+1

    __shared__ float s_lds[2][N_RES];   // double-buffered state (16 KB)
    __shared__ float x_lds[2][K_IN];    // double-buffered input row (4 KB)

    // ---- weights: bf16 path = 40 dwords/lane, held in registers ----
    uint2 wrp[16], wip[4];
    if constexpr (BF16W) {
        const u16* wr_row = Wres_bf + (size_t)row * N_RES + 4 * c32;
        #pragma unroll
        for (int i = 0; i < 16; ++i)
            wrp[i] = *reinterpret_cast<const uint2*>(wr_row + 128 * i);
        const u16* wi_row = Win_bf + (size_t)row * K_IN + 4 * c32;
        #pragma unroll
        for (int i = 0; i < 4; ++i)
            wip[i] = *reinterpret_cast<const uint2*>(wi_row + 128 * i);
    }

    // out row 0 = initial state
    if (blk == 0)
        for (int j = tid; j < N_RES; j += B_THREADS) out[j] = state0[j];

    // stage s_0 and x_0 (first in-loop barrier covers visibility)
    for (int j = tid; j < N_RES; j += B_THREADS) s_lds[0][j] = state0[j];
    if (tid < K_IN / 4)
        *reinterpret_cast<float4*>(&x_lds[0][4 * tid]) =
            *reinterpret_cast<const float4*>(input + 4 * tid);

    for (int t = 0; t < T_SEQ; ++t) {
        const int buf = t & 1;

        // stage x_{t+1}: issue the global load now (latency hides under poll),
        // LDS write after the poll, visible after the barrier.
        float4 xst;
        const bool do_stage = (tid < K_IN / 4) && (t + 1 < T_SEQ);
        if (do_stage)
            xst = *reinterpret_cast<const float4*>(
                      input + (size_t)(t + 1) * K_IN + 4 * tid);

        if (t > 0) {
            // ---- single-entry poll: thread tid owns packet tid (rows 2tid,2tid+1)
            const float phi = ((t >> 1) & 1) ? -1.0f : 1.0f;
            const u64* rp = ring + (buf << 10) + tid;
            float lo, hi;
            for (;;) {
                u64 e = __hip_atomic_load(rp, __ATOMIC_RELAXED,
                                          __HIP_MEMORY_SCOPE_AGENT);
                lo = __uint_as_float((u32)e);
                hi = __uint_as_float((u32)(e >> 32));
                if (phi * lo > ENC_THR && phi * hi > ENC_THR) break;
            }
            *reinterpret_cast<float2*>(&s_lds[buf][2 * tid]) =
                make_float2(fmaf(phi, lo, -ENC_OFF), fmaf(phi, hi, -ENC_OFF));
        }
        if (do_stage)
            *reinterpret_cast<float4*>(&x_lds[(t + 1) & 1][4 * tid]) = xst;
        __syncthreads();

        // ---- dot: row 'row', this lane covers cols {4*c32 + 128*i} ----
        float a = 0.0f;
        #pragma unroll
        for (int i = 0; i < 4; ++i) {
            float4 x = *reinterpret_cast<const float4*>(&x_lds[buf][4 * c32 + 128 * i]);
            if constexpr (BF16W) {
                float2 w01 = bf2(wip[i].x), w23 = bf2(wip[i].y);
                a = fmaf(w01.x, x.x, a); a = fmaf(w01.y, x.y, a);
                a = fmaf(w23.x, x.z, a); a = fmaf(w23.y, x.w, a);
            } else {
                float4 w = *reinterpret_cast<const float4*>(
                    W_in + (size_t)row * K_IN + 4 * c32 + 128 * i);
                a = fmaf(w.x, x.x, a); a = fmaf(w.y, x.y, a);
                a = fmaf(w.z, x.z, a); a = fmaf(w.w, x.w, a);
            }
        }
        #pragma unroll
        for (int i = 0; i < 16; ++i) {
            float4 s = *reinterpret_cast<const float4*>(&s_lds[buf][4 * c32 + 128 * i]);
            if constexpr (BF16W) {
                float2 w01 = bf2(wrp[i].x), w23 = bf2(wrp[i].y);
                a = fmaf(w01.x, s.x, a); a = fmaf(w01.y, s.y, a);
                a = fmaf(w23.x, s.z, a); a = fmaf(w23.y, s.w, a);
            } else {
                float4 w = *reinterpret_cast<const float4*>(
                    W_res + (size_t)row * N_RES + 4 * c32 + 128 * i);
                a = fmaf(w.x, s.x, a); a = fmaf(w.y, s.y, a);
                a = fmaf(w.z, s.z, a); a = fmaf(w.w, s.w, a);
            }
        }

        // ---- reduce within the 32-lane row group (5 hops, 1 acc) ----
        #pragma unroll
        for (int off = 16; off > 0; off >>= 1)
            a += __shfl_xor(a, off, 64);

        // lane 0 holds row 2e, lane 32 holds row 2e+1
        float v  = fast_tanh(a) * INV_SQRT_N;
        float vo = __shfl_xor(v, 32, 64);
        if (lane == 0) {
            const int   slotn = (t + 1) & 1;
            const float phin  = (((t + 1) >> 1) & 1) ? -1.0f : 1.0f;
            u64 pk = (u64)__float_as_uint(phin * (v + ENC_OFF)) |
                     ((u64)__float_as_uint(phin * (vo + ENC_OFF)) << 32);
            __hip_atomic_store(ring + (slotn << 10) + entry, pk,
                               __ATOMIC_RELAXED, __HIP_MEMORY_SCOPE_AGENT);
            *reinterpret_cast<float2*>(out + (size_t)(t + 1) * N_RES + 2 * entry) =
                make_float2(v, vo);
        }
    }
}

extern "C" void kernel_launch(void* const* d_in, const int* in_sizes, int n_in,
                              void* d_out, int out_size, void* d_ws, size_t ws_size,
                              hipStream_t stream) {
    const float* input  = (const float*)d_in[0];
    const float* state0 = (const float*)d_in[1];
    const float* W_in   = (const float*)d_in[2];
    const float* W_res  = (const float*)d_in[3];
    float* out = (float*)d_out;
    u64* ring  = (u64*)d_ws;

    // zero = "not ready" for both ring phases; re-cleared on every call/replay
    hipMemsetAsync(d_ws, 0, 2 * 1024 * sizeof(u64), stream);

    const size_t WRES_OFF = 65536;
    const size_t WIN_OFF  = WRES_OFF + (size_t)N_RES * N_RES * sizeof(u16);
    const size_t NEED     = WIN_OFF + (size_t)N_RES * K_IN * sizeof(u16);

    if (ws_size >= NEED) {
        u16* wres_bf = (u16*)((char*)d_ws + WRES_OFF);
        u16* win_bf  = (u16*)((char*)d_ws + WIN_OFF);
        repack_bf16<<<(N_RES * N_RES + 1023) / 1024, 1024, 0, stream>>>(
            W_res, wres_bf, N_RES * N_RES);
        repack_bf16<<<(N_RES * K_IN + 1023) / 1024, 1024, 0, stream>>>(
            W_in, win_bf, N_RES * K_IN);
        const u16* cwres = wres_bf;
        const u16* cwin  = win_bf;
        void* args[] = { (void*)&input, (void*)&state0, (void*)&W_in, (void*)&W_res,
                         (void*)&cwres, (void*)&cwin, (void*)&out, (void*)&ring };
        hipLaunchCooperativeKernel((const void*)reservoir_v8<true>,
                                   dim3(G_BLOCKS), dim3(B_THREADS),
                                   args, 0, stream);
    } else {
        const u16* cwres = nullptr;
        const u16* cwin  = nullptr;
        void* args[] = { (void*)&input, (void*)&state0, (void*)&W_in, (void*)&W_res,
                         (void*)&cwres, (void*)&cwin, (void*)&out, (void*)&ring };
        hipLaunchCooperativeKernel((const void*)reservoir_v8<false>,
                                   dim3(G_BLOCKS), dim3(B_THREADS),
                                   args, 0, stream);
    }
}

// Round 9
// 18835.977 us; speedup vs baseline: 12.7147x; 1.5898x over previous
//
#include <hip/hip_runtime.h>

// Problem constants
#define T_SEQ   8192
#define N_RES   2048
#define K_IN    512

// Geometry: 64 blocks x 512 threads (8 waves); 32 rows/block, 4 rows/wave.
#define G_BLOCKS 64
#define B_THREADS 512
#define ROWS_PER_WAVE 4
#define ROWS_PER_BLOCK 32
static_assert(G_BLOCKS * ROWS_PER_BLOCK == N_RES, "row partition mismatch");

#define INV_SQRT_N 0.022097086912079612f

// Phase encoding: packet float e = phi*(v + ENC_OFF), phi alternates per ring
// generation (phi(g) = ((g>>1)&1) ? -1 : +1, slot = g&1). |v| <= 0.0222 so
// |e| in [0.078, 0.122]. Ready iff phi_expected*e > ENC_THR; stale (gen-2)
// packet has opposite phi -> not-ready; zero-init -> not-ready.
#define ENC_OFF 0.1f
#define ENC_THR 0.05f

typedef unsigned long long u64;
typedef unsigned int u32;
typedef float f32x2 __attribute__((ext_vector_type(2)));

__device__ __forceinline__ float fast_tanh(float v) {
    float e = __expf(2.0f * v);
    return 1.0f - 2.0f / (e + 1.0f);
}

// In-loop register pin on a 64-bit pair (defeats reload/remat across the
// back edge; same discipline as v6 which measured best).
#define KEEP2(v) asm("" : "+v"(v))

// d_ws layout: ring [2][1024] u64 (16 KB)
__global__ __launch_bounds__(B_THREADS, 2)
void reservoir_v9(const float* __restrict__ input,   // [T_SEQ][K_IN]
                  const float* __restrict__ state0,  // [N_RES]
                  const float* __restrict__ W_in,    // [N_RES][K_IN]
                  const float* __restrict__ W_res,   // [N_RES][N_RES]
                  float* __restrict__ out,           // [T_SEQ+1][N_RES]
                  u64* __restrict__ ring)
{
    const int tid  = threadIdx.x;
    const int lane = tid & 63;
    const int wave = tid >> 6;
    const int blk  = blockIdx.x;
    const int r0   = blk * ROWS_PER_BLOCK + wave * ROWS_PER_WAVE;

    __shared__ float s_lds[2][N_RES];   // double-buffered state (16 KB)

    // ---- persistent weights as packed f32x2: lane l owns cols {4l+256i} ----
    f32x2 wr2[ROWS_PER_WAVE][16];   // W_res row k, 16 pairs = 32 cols
    f32x2 wi2[ROWS_PER_WAVE][4];    // W_in  row k, 4 pairs = 8 cols
    #pragma unroll
    for (int k = 0; k < ROWS_PER_WAVE; ++k) {
        const float* rrow = W_res + (size_t)(r0 + k) * N_RES;
        #pragma unroll
        for (int i = 0; i < 8; ++i) {
            float4 w = *reinterpret_cast<const float4*>(rrow + 4 * lane + 256 * i);
            wr2[k][2 * i]     = (f32x2){w.x, w.y};
            wr2[k][2 * i + 1] = (f32x2){w.z, w.w};
        }
        const float* irow = W_in + (size_t)(r0 + k) * K_IN;
        #pragma unroll
        for (int i = 0; i < 2; ++i) {
            float4 w = *reinterpret_cast<const float4*>(irow + 4 * lane + 256 * i);
            wi2[k][2 * i]     = (f32x2){w.x, w.y};
            wi2[k][2 * i + 1] = (f32x2){w.z, w.w};
        }
    }

    // out row 0 = initial state
    if (blk == 0)
        for (int j = tid; j < N_RES; j += B_THREADS) out[j] = state0[j];

    // s_0 -> LDS buffer 0 (covered by the in-loop __syncthreads at t=0)
    #pragma unroll
    for (int i = 0; i < 4; ++i)
        s_lds[0][i * 512 + tid] = state0[i * 512 + tid];

    // x row 0 as packed pairs (layout matches wi cols {4l+256i})
    f32x2 xv[4];
    {
        float4 a = *reinterpret_cast<const float4*>(input + 4 * lane);
        float4 b = *reinterpret_cast<const float4*>(input + 4 * lane + 256);
        xv[0] = (f32x2){a.x, a.y}; xv[1] = (f32x2){a.z, a.w};
        xv[2] = (f32x2){b.x, b.y}; xv[3] = (f32x2){b.z, b.w};
    }

    for (int t = 0; t < T_SEQ; ++t) {
        const int buf = t & 1;

        // issue x_{t+1} prefetch before the spin so HBM latency hides under it
        f32x2 xn[4] = {xv[0], xv[1], xv[2], xv[3]};
        if (t + 1 < T_SEQ) {
            const float* xr = input + (size_t)(t + 1) * K_IN;
            float4 a = *reinterpret_cast<const float4*>(xr + 4 * lane);
            float4 b = *reinterpret_cast<const float4*>(xr + 4 * lane + 256);
            xn[0] = (f32x2){a.x, a.y}; xn[1] = (f32x2){a.z, a.w};
            xn[2] = (f32x2){b.x, b.y}; xn[3] = (f32x2){b.z, b.w};
        }

        if (t > 0) {
            // ---- paced coalesced poll: 2 u64/thread covers the 1024-entry slot ----
            const u64* rp = ring + (buf << 10);
            const float phi = ((t >> 1) & 1) ? -1.0f : 1.0f;
            float2 sv2[2];
            u32 pend = 0x3u;
            while (pend) {
                #pragma unroll
                for (int i = 0; i < 2; ++i) {
                    if (pend & (1u << i)) {
                        u64 e = __hip_atomic_load(rp + i * 512 + tid,
                                                  __ATOMIC_RELAXED, __HIP_MEMORY_SCOPE_AGENT);
                        float lo = __uint_as_float((u32)e);
                        float hi = __uint_as_float((u32)(e >> 32));
                        if (phi * lo > ENC_THR && phi * hi > ENC_THR) {
                            sv2[i] = make_float2(fmaf(phi, lo, -ENC_OFF),
                                                 fmaf(phi, hi, -ENC_OFF));
                            pend &= ~(1u << i);
                        }
                    }
                }
                if (pend) __builtin_amdgcn_s_sleep(1);   // ~64cy backoff
            }
            #pragma unroll
            for (int i = 0; i < 2; ++i)
                *reinterpret_cast<float2*>(&s_lds[buf][2 * (i * 512 + tid)]) = sv2[i];
        }
        __syncthreads();

        // ---- state fragment from LDS as packed pairs ----
        f32x2 sp[16];
        #pragma unroll
        for (int i = 0; i < 8; ++i) {
            float4 s = *reinterpret_cast<const float4*>(&s_lds[buf][4 * lane + 256 * i]);
            sp[2 * i]     = (f32x2){s.x, s.y};
            sp[2 * i + 1] = (f32x2){s.z, s.w};
        }

        // ---- packed dots: v_pk_fma_f32, 2 MACs/instr, 4 rows in flight ----
        f32x2 acc2[ROWS_PER_WAVE];
        #pragma unroll
        for (int k = 0; k < ROWS_PER_WAVE; ++k) {
            f32x2 a = (f32x2){0.0f, 0.0f};
            #pragma unroll
            for (int i = 0; i < 4; ++i)
                a = __builtin_elementwise_fma(wi2[k][i], xv[i], a);
            #pragma unroll
            for (int i = 0; i < 16; ++i)
                a = __builtin_elementwise_fma(wr2[k][i], sp[i], a);
            acc2[k] = a;
        }

        // ---- horizontal + full-wave butterfly reduce (4 rows in flight) ----
        float acc[ROWS_PER_WAVE];
        #pragma unroll
        for (int k = 0; k < ROWS_PER_WAVE; ++k) acc[k] = acc2[k].x + acc2[k].y;
        #pragma unroll
        for (int off = 32; off > 0; off >>= 1) {
            #pragma unroll
            for (int k = 0; k < ROWS_PER_WAVE; ++k)
                acc[k] += __shfl_xor(acc[k], off, 64);
        }

        // ---- finalize: publish first (critical path), out store off-path ----
        const float v0 = fast_tanh(acc[0]) * INV_SQRT_N;
        const float v1 = fast_tanh(acc[1]) * INV_SQRT_N;
        const float v2 = fast_tanh(acc[2]) * INV_SQRT_N;
        const float v3 = fast_tanh(acc[3]) * INV_SQRT_N;
        const int   slotn = (t + 1) & 1;
        const float phin  = (((t + 1) >> 1) & 1) ? -1.0f : 1.0f;
        if (lane == 0) {
            u64 pk = (u64)__float_as_uint(phin * (v0 + ENC_OFF)) |
                     ((u64)__float_as_uint(phin * (v1 + ENC_OFF)) << 32);
            __hip_atomic_store(ring + (slotn << 10) + (r0 >> 1), pk,
                               __ATOMIC_RELAXED, __HIP_MEMORY_SCOPE_AGENT);
        } else if (lane == 1) {
            u64 pk = (u64)__float_as_uint(phin * (v2 + ENC_OFF)) |
                     ((u64)__float_as_uint(phin * (v3 + ENC_OFF)) << 32);
            __hip_atomic_store(ring + (slotn << 10) + (r0 >> 1) + 1, pk,
                               __ATOMIC_RELAXED, __HIP_MEMORY_SCOPE_AGENT);
        } else if (lane == 2) {
            // per-wave out store (rows r0..r0+3) — lane-scoped, not tid-scoped
            *reinterpret_cast<float4*>(out + (size_t)(t + 1) * N_RES + r0) =
                make_float4(v0, v1, v2, v3);
        }

        // ---- pin weights across the back edge (defeats reload/remat) ----
        #pragma unroll
        for (int k = 0; k < ROWS_PER_WAVE; ++k) {
            #pragma unroll
            for (int i = 0; i < 16; ++i) KEEP2(wr2[k][i]);
            #pragma unroll
            for (int i = 0; i < 4; ++i)  KEEP2(wi2[k][i]);
        }

        #pragma unroll
        for (int i = 0; i < 4; ++i) xv[i] = xn[i];
    }
}

extern "C" void kernel_launch(void* const* d_in, const int* in_sizes, int n_in,
                              void* d_out, int out_size, void* d_ws, size_t ws_size,
                              hipStream_t stream) {
    const float* input  = (const float*)d_in[0];
    const float* state0 = (const float*)d_in[1];
    const float* W_in   = (const float*)d_in[2];
    const float* W_res  = (const float*)d_in[3];
    float* out = (float*)d_out;
    u64* ring  = (u64*)d_ws;

    // zero = "not ready" for both phases; re-cleared on every call/replay
    hipMemsetAsync(d_ws, 0, 2 * (N_RES / 2) * sizeof(u64), stream);

    void* args[] = { (void*)&input, (void*)&state0, (void*)&W_in, (void*)&W_res,
                     (void*)&out, (void*)&ring };
    hipLaunchCooperativeKernel((const void*)reservoir_v9,
                               dim3(G_BLOCKS), dim3(B_THREADS),
                               args, 0, stream);
}